// Round 5
// baseline (254.184 us; speedup 1.0000x reference)
//
#include <hip/hip_runtime.h>
#include <hip/hip_bf16.h>

typedef __hip_bfloat16 bf16;
typedef __attribute__((ext_vector_type(8))) short short8;

static constexpr int NPOS = 65536;  // 64*64*16

// bf16 bits (as short) -> float
__device__ __forceinline__ float bs2f(short s) {
  union { float f; unsigned u; } cv;
  cv.u = ((unsigned)(unsigned short)s) << 16;
  return cv.f;
}
// float -> bf16 bits (as short), RNE
__device__ __forceinline__ short f2bs(float f) {
  bf16 b = __float2bfloat16(f);
  short r;
  __builtin_memcpy(&r, &b, 2);
  return r;
}

// trilinear upsample of channel slab xc (32,32,8) evaluated at output (h,w,z)
// of the (64,64,16) grid; matches reference: pos=i*(L-1)/(2L-1), i0=clip(floor,0,L-2)
__device__ __forceinline__ float upsample_at(const float* __restrict__ xc,
                                             int h, int w, int z) {
  float fh = (float)h * (31.0f / 63.0f);
  float fw = (float)w * (31.0f / 63.0f);
  float fz = (float)z * (7.0f / 15.0f);
  int ih = (int)fh; if (ih > 30) ih = 30;
  int iw = (int)fw; if (iw > 30) iw = 30;
  int iz = (int)fz; if (iz > 6) iz = 6;
  float wh = fh - (float)ih, ww = fw - (float)iw, wz = fz - (float)iz;
  const float* xb = xc + ih * 256 + iw * 8 + iz;
  float v000 = xb[0],   v001 = xb[1];
  float v010 = xb[8],   v011 = xb[9];
  float v100 = xb[256], v101 = xb[257];
  float v110 = xb[264], v111 = xb[265];
  float v00 = v000 * (1.f - wz) + v001 * wz;
  float v01 = v010 * (1.f - wz) + v011 * wz;
  float v10 = v100 * (1.f - wz) + v101 * wz;
  float v11 = v110 * (1.f - wz) + v111 * wz;
  float v0 = v00 * (1.f - ww) + v01 * ww;
  float v1 = v10 * (1.f - ww) + v11 * ww;
  return v0 * (1.f - wh) + v1 * wh;
}

// K1: per-channel instance-norm stats. blocks 0..63 -> upsampled-x channels
// (recomputed on the fly, no xu materialization), blocks 64..127 -> skip.
// stats: [mean_xu(64), rstd_xu(64), mean_sk(64), rstd_sk(64)]
__global__ __launch_bounds__(256) void k_stats(const float* __restrict__ x,
                                               const float* __restrict__ skip,
                                               float* __restrict__ stats) {
  __shared__ float s1[256];
  __shared__ float s2[256];
  int b = blockIdx.x, tid = threadIdx.x;
  float sum = 0.f, sq = 0.f;
  if (b < 64) {
    const float* xc = x + b * 8192;
    for (int i = tid; i < NPOS; i += 256) {
      int h = i >> 10, w = (i >> 4) & 63, z = i & 15;
      float v = upsample_at(xc, h, w, z);
      sum += v; sq += v * v;
    }
  } else {
    const float* p = skip + (size_t)(b - 64) * NPOS;
    for (int i = tid; i < NPOS; i += 256) {
      float v = p[i]; sum += v; sq += v * v;
    }
  }
  s1[tid] = sum; s2[tid] = sq;
  __syncthreads();
  for (int s = 128; s > 0; s >>= 1) {
    if (tid < s) { s1[tid] += s1[tid + s]; s2[tid] += s2[tid + s]; }
    __syncthreads();
  }
  if (tid == 0) {
    float m = s1[0] * (1.0f / NPOS);
    float var = s2[0] * (1.0f / NPOS) - m * m;
    int c = b & 63;
    int off = (b < 64) ? 0 : 128;
    stats[off + c] = m;
    stats[off + 64 + c] = rsqrtf(var + 1e-5f);
  }
}

// K2: recompute upsample + instance-norm + K/V projection. k/v stored
// pos-major bf16: kbuf[pos*64 + j]. 64 positions per block.
__global__ __launch_bounds__(256) void k_proj_kv(
    const float* __restrict__ x, const float* __restrict__ stats,
    const float* __restrict__ Wk, const float* __restrict__ bk,
    const float* __restrict__ Wv, const float* __restrict__ bv,
    bf16* __restrict__ kbuf, bf16* __restrict__ vbuf) {
  __shared__ float xt[4096];  // [c][t] 64x64 normalized upsampled values
  __shared__ float wk[4096];
  __shared__ float wv[4096];
  int tid = threadIdx.x;
  int p0 = blockIdx.x * 64;
  for (int i = tid; i < 4096; i += 256) {
    wk[i] = Wk[i];
    wv[i] = Wv[i];
    int c = i >> 6, t = i & 63;
    int p = p0 + t;
    int h = p >> 10, w = (p >> 4) & 63, z = p & 15;
    float v = upsample_at(x + c * 8192, h, w, z);
    xt[i] = (v - stats[c]) * stats[64 + c];
  }
  __syncthreads();
  int t = tid & 63;
  int jb = (tid >> 6) * 16;  // each quarter of the block does 16 of 64 outputs
  size_t p = (size_t)(p0 + t);
  for (int jc = 0; jc < 16; jc += 8) {
    int j0 = jb + jc;
    float ak[8], av[8];
#pragma unroll
    for (int u = 0; u < 8; u++) { ak[u] = bk[j0 + u]; av[u] = bv[j0 + u]; }
    for (int c = 0; c < 64; c++) {
      float xv = xt[c * 64 + t];
      const float* wkr = &wk[c * 64 + j0];
      const float* wvr = &wv[c * 64 + j0];
#pragma unroll
      for (int u = 0; u < 8; u++) { ak[u] += xv * wkr[u]; av[u] += xv * wvr[u]; }
    }
    short8 ks, vs;
#pragma unroll
    for (int u = 0; u < 8; u++) { ks[u] = f2bs(ak[u]); vs[u] = f2bs(av[u]); }
    *(short8*)(kbuf + p * 64 + j0) = ks;
    *(short8*)(vbuf + p * 64 + j0) = vs;
  }
}

// K3: fused skip-norm + Q projection + 27-neighbor attention (online softmax
// with relative position bias) + output projection + transposed fp32 store.
// 32 positions/block, 8 threads per position (one per head).
__global__ __launch_bounds__(256) void k_attn(
    const float* __restrict__ skip, const float* __restrict__ stats,
    const float* __restrict__ Wq, const float* __restrict__ bq,
    const float* __restrict__ Wo, const float* __restrict__ bo,
    const float* __restrict__ rpb,
    const bf16* __restrict__ kbuf, const bf16* __restrict__ vbuf,
    float* __restrict__ out) {
  __shared__ float wq[4096];
  __shared__ float wo[4096];
  __shared__ float rp[1000];
  __shared__ float bql[64];
  __shared__ float bol[64];
  __shared__ float skT[64 * 33];  // [c][t], padded
  __shared__ float oT[32 * 65];   // [pos][j], padded to kill 32-way conflicts
  int tid = threadIdx.x;
  int p0 = blockIdx.x * 32;
  for (int i = tid; i < 4096; i += 256) { wq[i] = Wq[i]; wo[i] = Wo[i]; }
  for (int i = tid; i < 1000; i += 256) rp[i] = rpb[i];
  if (tid < 64) { bql[tid] = bq[tid]; bol[tid] = bo[tid]; }
  for (int i = tid; i < 64 * 32; i += 256) {
    int c = i >> 5, t = i & 31;
    skT[c * 33 + t] =
        (skip[(size_t)c * NPOS + p0 + t] - stats[128 + c]) * stats[192 + c];
  }
  __syncthreads();

  int head = tid & 7, pp = tid >> 3;
  int p = p0 + pp;
  int h = p >> 10, w = (p >> 4) & 63, z = p & 15;

  // q projection for this head (8 dims)
  float q[8];
#pragma unroll
  for (int d = 0; d < 8; d++) q[d] = bql[head * 8 + d];
  for (int c = 0; c < 64; c++) {
    float sv = skT[c * 33 + pp];
    const float* wr = &wq[c * 64 + head * 8];
#pragma unroll
    for (int d = 0; d < 8; d++) q[d] += sv * wr[d];
  }
  const float scale = 0.35355339059327373f;  // 8^-0.5
#pragma unroll
  for (int d = 0; d < 8; d++) q[d] *= scale;

  int sh = h - 1; if (sh < 0) sh = 0; if (sh > 61) sh = 61;
  int sw = w - 1; if (sw < 0) sw = 0; if (sw > 61) sw = 61;
  int sz = z - 1; if (sz < 0) sz = 0; if (sz > 13) sz = 13;

  float mrun = -1e30f, lrun = 0.f;
  float oa[8];
#pragma unroll
  for (int d = 0; d < 8; d++) oa[d] = 0.f;
  const float* rph = &rp[head * 125];

  for (int kh = 0; kh < 3; kh++) {
    for (int kw = 0; kw < 3; kw++) {
      for (int kz = 0; kz < 3; kz++) {
        int nh = sh + kh, nw = sw + kw, nz = sz + kz;
        size_t np_ = (size_t)(nh * 1024 + nw * 16 + nz);
        short8 k8 = *(const short8*)(kbuf + np_ * 64 + head * 8);
        float s = q[0] * bs2f(k8[0]) + q[1] * bs2f(k8[1]) +
                  q[2] * bs2f(k8[2]) + q[3] * bs2f(k8[3]) +
                  q[4] * bs2f(k8[4]) + q[5] * bs2f(k8[5]) +
                  q[6] * bs2f(k8[6]) + q[7] * bs2f(k8[7]);
        int rh = nh - h + 2, rw = nw - w + 2, rz = nz - z + 2;
        s += rph[(rh * 5 + rw) * 5 + rz];
        float nm = fmaxf(mrun, s);
        float alpha = __expf(mrun - nm);
        float pw = __expf(s - nm);
        lrun = lrun * alpha + pw;
        short8 v8 = *(const short8*)(vbuf + np_ * 64 + head * 8);
#pragma unroll
        for (int d = 0; d < 8; d++) oa[d] = oa[d] * alpha + pw * bs2f(v8[d]);
        mrun = nm;
      }
    }
  }
  float inv = 1.0f / lrun;
#pragma unroll
  for (int d = 0; d < 8; d++) oT[pp * 65 + head * 8 + d] = oa[d] * inv;
  __syncthreads();

  // output projection: group g handles channels g*8..g*8+7, lane l = position
  int g = tid >> 5, l = tid & 31;
  float acc[8];
#pragma unroll
  for (int u = 0; u < 8; u++) acc[u] = bol[g * 8 + u];
  for (int j = 0; j < 64; j++) {
    float ov = oT[l * 65 + j];
    const float* wr = &wo[j * 64 + g * 8];
#pragma unroll
    for (int u = 0; u < 8; u++) acc[u] += ov * wr[u];
  }
#pragma unroll
  for (int u = 0; u < 8; u++)
    out[(size_t)(g * 8 + u) * NPOS + p0 + l] = acc[u];
}

extern "C" void kernel_launch(void* const* d_in, const int* in_sizes, int n_in,
                              void* d_out, int out_size, void* d_ws, size_t ws_size,
                              hipStream_t stream) {
  const float* x    = (const float*)d_in[0];
  const float* skip = (const float*)d_in[1];
  const float* Wq   = (const float*)d_in[2];
  const float* bq   = (const float*)d_in[3];
  const float* Wk   = (const float*)d_in[4];
  const float* bk   = (const float*)d_in[5];
  const float* Wv   = (const float*)d_in[6];
  const float* bv   = (const float*)d_in[7];
  const float* Wo   = (const float*)d_in[8];
  const float* bo   = (const float*)d_in[9];
  const float* rpb  = (const float*)d_in[10];

  // ws layout (total 16 MB + 1 KB):
  bf16* kbuf   = (bf16*)d_ws;                                 // 4,194,304 bf16 (8 MB)
  bf16* vbuf   = (bf16*)((char*)d_ws + ((size_t)8 << 20));    // 4,194,304 bf16 (8 MB)
  float* stats = (float*)((char*)d_ws + ((size_t)16 << 20));  // 256 fp32
  float* out = (float*)d_out;

  hipLaunchKernelGGL(k_stats, dim3(128), dim3(256), 0, stream, x, skip, stats);
  hipLaunchKernelGGL(k_proj_kv, dim3(1024), dim3(256), 0, stream, x, stats,
                     Wk, bk, Wv, bv, kbuf, vbuf);
  hipLaunchKernelGGL(k_attn, dim3(2048), dim3(256), 0, stream, skip, stats,
                     Wq, bq, Wo, bo, rpb, kbuf, vbuf, out);
}

// Round 6
// 201.787 us; speedup vs baseline: 1.2597x; 1.2597x over previous
//
#include <hip/hip_runtime.h>
#include <hip/hip_bf16.h>

typedef __hip_bfloat16 bf16;
typedef __attribute__((ext_vector_type(8))) short short8;

static constexpr int NPOS = 65536;  // 64*64*16

// bf16 bits (as short) -> float
__device__ __forceinline__ float bs2f(short s) {
  union { float f; unsigned u; } cv;
  cv.u = ((unsigned)(unsigned short)s) << 16;
  return cv.f;
}
// float -> bf16 bits (as short), RNE
__device__ __forceinline__ short f2bs(float f) {
  bf16 b = __float2bfloat16(f);
  short r;
  __builtin_memcpy(&r, &b, 2);
  return r;
}

// trilinear upsample of channel slab xc (32,32,8) evaluated at output (h,w,z)
// of the (64,64,16) grid; matches reference: pos=i*(L-1)/(2L-1), i0=clip(floor,0,L-2)
__device__ __forceinline__ float upsample_at(const float* __restrict__ xc,
                                             int h, int w, int z) {
  float fh = (float)h * (31.0f / 63.0f);
  float fw = (float)w * (31.0f / 63.0f);
  float fz = (float)z * (7.0f / 15.0f);
  int ih = (int)fh; if (ih > 30) ih = 30;
  int iw = (int)fw; if (iw > 30) iw = 30;
  int iz = (int)fz; if (iz > 6) iz = 6;
  float wh = fh - (float)ih, ww = fw - (float)iw, wz = fz - (float)iz;
  const float* xb = xc + ih * 256 + iw * 8 + iz;
  float v000 = xb[0],   v001 = xb[1];
  float v010 = xb[8],   v011 = xb[9];
  float v100 = xb[256], v101 = xb[257];
  float v110 = xb[264], v111 = xb[265];
  float v00 = v000 * (1.f - wz) + v001 * wz;
  float v01 = v010 * (1.f - wz) + v011 * wz;
  float v10 = v100 * (1.f - wz) + v101 * wz;
  float v11 = v110 * (1.f - wz) + v111 * wz;
  float v0 = v00 * (1.f - ww) + v01 * ww;
  float v1 = v10 * (1.f - ww) + v11 * ww;
  return v0 * (1.f - wh) + v1 * wh;
}

// K1a: partial instance-norm sums. blocks 0..511: upsampled-x channel c=b>>3,
// chunk b&7 (8192 positions). blocks 512..1023: skip. Deterministic tree.
__global__ __launch_bounds__(256) void k_partial(const float* __restrict__ x,
                                                 const float* __restrict__ skip,
                                                 float* __restrict__ partials) {
  __shared__ float s1[256];
  __shared__ float s2[256];
  int b = blockIdx.x, tid = threadIdx.x;
  float sum = 0.f, sq = 0.f;
  if (b < 512) {
    int c = b >> 3, base = (b & 7) * 8192;
    const float* xc = x + c * 8192;
    for (int i = tid; i < 8192; i += 256) {
      int pos = base + i;
      int h = pos >> 10, w = (pos >> 4) & 63, z = pos & 15;
      float v = upsample_at(xc, h, w, z);
      sum += v; sq += v * v;
    }
  } else {
    int bb = b - 512;
    const float* p = skip + (size_t)(bb >> 3) * NPOS + (bb & 7) * 8192;
    for (int i = tid; i < 8192; i += 256) { float v = p[i]; sum += v; sq += v * v; }
  }
  s1[tid] = sum; s2[tid] = sq;
  __syncthreads();
  for (int s = 128; s > 0; s >>= 1) {
    if (tid < s) { s1[tid] += s1[tid + s]; s2[tid] += s2[tid + s]; }
    __syncthreads();
  }
  if (tid == 0) { partials[2 * b] = s1[0]; partials[2 * b + 1] = s2[0]; }
}

// K1b: finalize stats. stats: [mean_xu(64), rstd_xu(64), mean_sk(64), rstd_sk(64)]
__global__ __launch_bounds__(128) void k_finalize(const float* __restrict__ partials,
                                                  float* __restrict__ stats) {
  int t = threadIdx.x;
  int base = (t < 64) ? t * 8 : 512 + (t - 64) * 8;
  float sum = 0.f, sq = 0.f;
#pragma unroll
  for (int j = 0; j < 8; j++) {
    sum += partials[2 * (base + j)];
    sq  += partials[2 * (base + j) + 1];
  }
  float m = sum * (1.0f / NPOS);
  float var = sq * (1.0f / NPOS) - m * m;
  int off = (t < 64) ? 0 : 128;
  int c = t & 63;
  stats[off + c] = m;
  stats[off + 64 + c] = rsqrtf(var + 1e-5f);
}

// K2: recompute upsample + instance-norm + K/V projection. k/v stored
// pos-major bf16: kbuf[pos*64 + j]. 64 positions per block. Wk/Wv share one
// 16 KB LDS buffer (two passes) -> 32 KB total -> 5 blocks/CU.
__global__ __launch_bounds__(256, 5) void k_proj_kv(
    const float* __restrict__ x, const float* __restrict__ stats,
    const float* __restrict__ Wk, const float* __restrict__ bk,
    const float* __restrict__ Wv, const float* __restrict__ bv,
    bf16* __restrict__ kbuf, bf16* __restrict__ vbuf) {
  __shared__ float xt[4096];    // [c][t] 64x64 normalized upsampled values
  __shared__ float wbuf[4096];  // Wk, then Wv
  int tid = threadIdx.x;
  int p0 = blockIdx.x * 64;
  for (int i = tid; i < 4096; i += 256) {
    wbuf[i] = Wk[i];
    int c = i >> 6, t = i & 63;
    int p = p0 + t;
    int h = p >> 10, w = (p >> 4) & 63, z = p & 15;
    float v = upsample_at(x + c * 8192, h, w, z);
    xt[i] = (v - stats[c]) * stats[64 + c];
  }
  __syncthreads();
  int t = tid & 63;
  int j0 = (tid >> 6) * 16;  // this thread owns outputs j0..j0+15
  size_t p = (size_t)(p0 + t);

  // pass 1: K
  float a0[8], a1[8];
#pragma unroll
  for (int u = 0; u < 8; u++) { a0[u] = bk[j0 + u]; a1[u] = bk[j0 + 8 + u]; }
  for (int c = 0; c < 64; c++) {
    float xv = xt[c * 64 + t];
    const float* wr = &wbuf[c * 64 + j0];
#pragma unroll
    for (int u = 0; u < 8; u++) { a0[u] += xv * wr[u]; a1[u] += xv * wr[8 + u]; }
  }
  short8 s0, s1v;
#pragma unroll
  for (int u = 0; u < 8; u++) { s0[u] = f2bs(a0[u]); s1v[u] = f2bs(a1[u]); }
  *(short8*)(kbuf + p * 64 + j0) = s0;
  *(short8*)(kbuf + p * 64 + j0 + 8) = s1v;

  __syncthreads();  // all Wk reads done
  for (int i = tid; i < 4096; i += 256) wbuf[i] = Wv[i];
  __syncthreads();

  // pass 2: V
#pragma unroll
  for (int u = 0; u < 8; u++) { a0[u] = bv[j0 + u]; a1[u] = bv[j0 + 8 + u]; }
  for (int c = 0; c < 64; c++) {
    float xv = xt[c * 64 + t];
    const float* wr = &wbuf[c * 64 + j0];
#pragma unroll
    for (int u = 0; u < 8; u++) { a0[u] += xv * wr[u]; a1[u] += xv * wr[8 + u]; }
  }
#pragma unroll
  for (int u = 0; u < 8; u++) { s0[u] = f2bs(a0[u]); s1v[u] = f2bs(a1[u]); }
  *(short8*)(vbuf + p * 64 + j0) = s0;
  *(short8*)(vbuf + p * 64 + j0 + 8) = s1v;
}

// K3: fused skip-norm + Q projection + 27-neighbor attention (online softmax
// with rpb) + output projection + fp32 store. 32 positions/block, 8 threads
// per position (one per head). LDS ~29 KB: wbuf holds Wq then Wo; skoT holds
// skT (64x33) then oT (32x65). -> 5 blocks/CU.
__global__ __launch_bounds__(256, 5) void k_attn(
    const float* __restrict__ skip, const float* __restrict__ stats,
    const float* __restrict__ Wq, const float* __restrict__ bq,
    const float* __restrict__ Wo, const float* __restrict__ bo,
    const float* __restrict__ rpb,
    const bf16* __restrict__ kbuf, const bf16* __restrict__ vbuf,
    float* __restrict__ out) {
  __shared__ float wbuf[4096];  // Wq (phase 1), Wo (phase 3)
  __shared__ float rp[1000];
  __shared__ float bql[64];
  __shared__ float bol[64];
  __shared__ float skoT[2112];  // skT [c][t] stride 33, then oT [pos][j] stride 65
  int tid = threadIdx.x;
  int p0 = blockIdx.x * 32;
  for (int i = tid; i < 4096; i += 256) wbuf[i] = Wq[i];
  for (int i = tid; i < 1000; i += 256) rp[i] = rpb[i];
  if (tid < 64) { bql[tid] = bq[tid]; bol[tid] = bo[tid]; }
  for (int i = tid; i < 64 * 32; i += 256) {
    int c = i >> 5, t = i & 31;
    skoT[c * 33 + t] =
        (skip[(size_t)c * NPOS + p0 + t] - stats[128 + c]) * stats[192 + c];
  }
  __syncthreads();

  int head = tid & 7, pp = tid >> 3;
  int p = p0 + pp;
  int h = p >> 10, w = (p >> 4) & 63, z = p & 15;

  // q projection for this head (8 dims)
  float q[8];
#pragma unroll
  for (int d = 0; d < 8; d++) q[d] = bql[head * 8 + d];
  for (int c = 0; c < 64; c++) {
    float sv = skoT[c * 33 + pp];
    const float* wr = &wbuf[c * 64 + head * 8];
#pragma unroll
    for (int d = 0; d < 8; d++) q[d] += sv * wr[d];
  }
  const float scale = 0.35355339059327373f;  // 8^-0.5
#pragma unroll
  for (int d = 0; d < 8; d++) q[d] *= scale;

  __syncthreads();  // Wq + skT fully consumed; wbuf/skoT reusable

  // prefetch Wo into registers (issues before the gather; LDS write deferred)
  float wotmp[16];
#pragma unroll
  for (int ii = 0; ii < 16; ii++) wotmp[ii] = Wo[tid + 256 * ii];

  int sh = h - 1; if (sh < 0) sh = 0; if (sh > 61) sh = 61;
  int sw = w - 1; if (sw < 0) sw = 0; if (sw > 61) sw = 61;
  int sz = z - 1; if (sz < 0) sz = 0; if (sz > 13) sz = 13;

  float mrun = -1e30f, lrun = 0.f;
  float oa[8];
#pragma unroll
  for (int d = 0; d < 8; d++) oa[d] = 0.f;
  const float* rph = &rp[head * 125];

  for (int kh = 0; kh < 3; kh++) {
    for (int kw = 0; kw < 3; kw++) {
      for (int kz = 0; kz < 3; kz++) {
        int nh = sh + kh, nw = sw + kw, nz = sz + kz;
        size_t np_ = (size_t)(nh * 1024 + nw * 16 + nz);
        short8 k8 = *(const short8*)(kbuf + np_ * 64 + head * 8);
        float s = q[0] * bs2f(k8[0]) + q[1] * bs2f(k8[1]) +
                  q[2] * bs2f(k8[2]) + q[3] * bs2f(k8[3]) +
                  q[4] * bs2f(k8[4]) + q[5] * bs2f(k8[5]) +
                  q[6] * bs2f(k8[6]) + q[7] * bs2f(k8[7]);
        int rh = nh - h + 2, rw = nw - w + 2, rz = nz - z + 2;
        s += rph[(rh * 5 + rw) * 5 + rz];
        float nm = fmaxf(mrun, s);
        float alpha = __expf(mrun - nm);
        float pw = __expf(s - nm);
        lrun = lrun * alpha + pw;
        short8 v8 = *(const short8*)(vbuf + np_ * 64 + head * 8);
#pragma unroll
        for (int d = 0; d < 8; d++) oa[d] = oa[d] * alpha + pw * bs2f(v8[d]);
        mrun = nm;
      }
    }
  }
  float inv = 1.0f / lrun;
#pragma unroll
  for (int d = 0; d < 8; d++) skoT[pp * 65 + head * 8 + d] = oa[d] * inv;
#pragma unroll
  for (int ii = 0; ii < 16; ii++) wbuf[tid + 256 * ii] = wotmp[ii];
  __syncthreads();

  // output projection: group g handles channels g*8..g*8+7, lane l = position
  int g = tid >> 5, l = tid & 31;
  float acc[8];
#pragma unroll
  for (int u = 0; u < 8; u++) acc[u] = bol[g * 8 + u];
  for (int j = 0; j < 64; j++) {
    float ov = skoT[l * 65 + j];
    const float* wr = &wbuf[j * 64 + g * 8];
#pragma unroll
    for (int u = 0; u < 8; u++) acc[u] += ov * wr[u];
  }
#pragma unroll
  for (int u = 0; u < 8; u++)
    out[(size_t)(g * 8 + u) * NPOS + p0 + l] = acc[u];
}

extern "C" void kernel_launch(void* const* d_in, const int* in_sizes, int n_in,
                              void* d_out, int out_size, void* d_ws, size_t ws_size,
                              hipStream_t stream) {
  const float* x    = (const float*)d_in[0];
  const float* skip = (const float*)d_in[1];
  const float* Wq   = (const float*)d_in[2];
  const float* bq   = (const float*)d_in[3];
  const float* Wk   = (const float*)d_in[4];
  const float* bk   = (const float*)d_in[5];
  const float* Wv   = (const float*)d_in[6];
  const float* bv   = (const float*)d_in[7];
  const float* Wo   = (const float*)d_in[8];
  const float* bo   = (const float*)d_in[9];
  const float* rpb  = (const float*)d_in[10];

  // ws layout (total 16 MB + ~12 KB):
  bf16* kbuf     = (bf16*)d_ws;                                 // 8 MB
  bf16* vbuf     = (bf16*)((char*)d_ws + ((size_t)8 << 20));    // 8 MB
  float* stats   = (float*)((char*)d_ws + ((size_t)16 << 20));  // 256 fp32
  float* partials = stats + 256;                                // 2048 fp32
  float* out = (float*)d_out;

  hipLaunchKernelGGL(k_partial, dim3(1024), dim3(256), 0, stream, x, skip, partials);
  hipLaunchKernelGGL(k_finalize, dim3(1), dim3(128), 0, stream, partials, stats);
  hipLaunchKernelGGL(k_proj_kv, dim3(1024), dim3(256), 0, stream, x, stats,
                     Wk, bk, Wv, bv, kbuf, vbuf);
  hipLaunchKernelGGL(k_attn, dim3(2048), dim3(256), 0, stream, skip, stats,
                     Wq, bq, Wo, bo, rpb, kbuf, vbuf, out);
}